// Round 1
// baseline (1626.657 us; speedup 1.0000x reference)
//
#include <hip/hip_runtime.h>
#include <hip/hip_bf16.h>

// ModulatedConv2d: b=16, ic=oc=512, ks=3, sd=512, h=w=64
// out[b,oc,y,x] = demod[b,oc] * sum_{ic,ky,kx} weight[oc,ic,ky,kx]*s[b,ic]*x[b,ic,y+ky-1,x+kx-1] + bias[oc]
// Implemented as: (1) s = style@mod_w^T + mod_b  (2) wmod_bf16 = weight*s*demod
// (3) per-batch implicit-GEMM conv with bf16 MFMA: M=512(oc) N=4096(hw) K=4608(ic*9)

typedef __bf16 bf16x8 __attribute__((ext_vector_type(8)));
typedef float  f32x4  __attribute__((ext_vector_type(4)));

#define IC   512
#define OC   512
#define HW   4096
#define KTOT 4608   // IC*9
#define BM   128
#define BN   128
#define BK   32
#define BKP  40     // padded LDS row stride (elements); 40*2B=80B keeps 16B alignment

// ---------------- kernel 1: style modulation s[b][i] ----------------
__global__ __launch_bounds__(256) void style_mod_kernel(
    const float* __restrict__ style,   // [16,512]
    const float* __restrict__ mod_w,   // [512,512]
    const float* __restrict__ mod_b,   // [512]
    float* __restrict__ s_out)         // [16,512]
{
    int pair = blockIdx.x * 4 + (threadIdx.x >> 6);   // b*512 + i
    int lane = threadIdx.x & 63;
    int b = pair >> 9;
    int i = pair & 511;
    const float4* sv = (const float4*)(style + b * 512);
    const float4* wv = (const float4*)(mod_w + i * 512);
    float4 a0 = sv[lane * 2], a1 = sv[lane * 2 + 1];
    float4 w0 = wv[lane * 2], w1 = wv[lane * 2 + 1];
    float sum = a0.x*w0.x + a0.y*w0.y + a0.z*w0.z + a0.w*w0.w
              + a1.x*w1.x + a1.y*w1.y + a1.z*w1.z + a1.w*w1.w;
    #pragma unroll
    for (int off = 32; off; off >>= 1) sum += __shfl_xor(sum, off);
    if (lane == 0) s_out[pair] = sum + mod_b[i];
}

// ---------------- kernel 2: demod + bf16 modulated weights ----------------
__global__ __launch_bounds__(256) void wmod_kernel(
    const float* __restrict__ weight,  // [512,4608]
    const float* __restrict__ s_in,    // [16,512]
    __hip_bfloat16* __restrict__ wmod) // [16,512,4608]
{
    int b  = blockIdx.x >> 9;
    int oc = blockIdx.x & 511;
    __shared__ float s_sh[512];
    __shared__ float red[256];
    int t = threadIdx.x;
    s_sh[t]       = s_in[b * 512 + t];
    s_sh[t + 256] = s_in[b * 512 + t + 256];
    __syncthreads();
    const float* wrow = weight + (size_t)oc * KTOT;
    float partial = 0.f;
    for (int e = t; e < KTOT; e += 256) {
        float v = wrow[e] * s_sh[e / 9];
        partial += v * v;
    }
    red[t] = partial;
    __syncthreads();
    #pragma unroll
    for (int off = 128; off; off >>= 1) {
        if (t < off) red[t] += red[t + off];
        __syncthreads();
    }
    float demod = rsqrtf(red[0] + 1e-8f);
    __hip_bfloat16* dst = wmod + (size_t)blockIdx.x * KTOT;
    for (int e = t; e < KTOT; e += 256) {
        dst[e] = __float2bfloat16(wrow[e] * s_sh[e / 9] * demod);
    }
}

// ---------------- kernel 3: implicit-GEMM conv ----------------
__global__ __launch_bounds__(256) void conv_kernel(
    const float* __restrict__ x,             // [16,512,64,64]
    const __hip_bfloat16* __restrict__ wmod, // [16,512,4608]
    const float* __restrict__ bias,          // [512]
    float* __restrict__ out)                 // [16,512,64,64]
{
    __shared__ __align__(16) __hip_bfloat16 Ash[BM * BKP];
    __shared__ __align__(16) __hip_bfloat16 Bsh[BN * BKP];

    const int t    = threadIdx.x;
    const int lane = t & 63;
    const int wid  = t >> 6;
    const int wm   = wid >> 1;   // wave row (0..1)
    const int wn   = wid & 1;    // wave col (0..1)

    const int ntile  = blockIdx.x;   // 0..31
    const int octile = blockIdx.y;   // 0..3
    const int b      = blockIdx.z;   // 0..15

    const int oc0 = octile * BM;
    const int n0  = ntile * BN;
    const int y0  = n0 >> 6;         // 2 image rows per N-tile

    const float* xb = x + (size_t)b * IC * HW;
    const __hip_bfloat16* wb = wmod + (size_t)(b * OC + oc0) * KTOT;

    f32x4 acc[4][4] = {};

    // A staging: thread t loads 8 bf16 (16B) for rows t/4 and t/4+64
    const int arow  = t >> 2;
    const int akoff = (t & 3) * 8;
    // B staging: thread t handles local k = t/8, pixel segment (t%8)*16..+16
    const int bk    = t >> 3;
    const int seg   = t & 7;
    const int nbase = seg * 16;
    const int yloc  = nbase >> 6;    // 0 or 1
    const int col0  = nbase & 63;

    const int lr = lane & 15;
    const int lq = lane >> 4;

    for (int k0 = 0; k0 < KTOT; k0 += BK) {
        // ---- stage A (modulated weights, row-major K) ----
        {
            const __hip_bfloat16* src = wb + (size_t)arow * KTOT + k0 + akoff;
            uint4 v0 = *reinterpret_cast<const uint4*>(src);
            uint4 v1 = *reinterpret_cast<const uint4*>(src + (size_t)64 * KTOT);
            *reinterpret_cast<uint4*>(&Ash[arow * BKP + akoff]) = v0;
            *reinterpret_cast<uint4*>(&Ash[(arow + 64) * BKP + akoff]) = v1;
        }
        // ---- stage B (im2col from x, stored transposed [n][k]) ----
        {
            int k   = k0 + bk;
            int ic  = k / 9;
            int tap = k - ic * 9;
            int ky  = tap / 3;
            int kx  = tap - ky * 3;
            int sy  = y0 + yloc + ky - 1;
            bool rowok = (sy >= 0) && (sy < 64);
            const float* xrow = xb + ((long)ic * 64 + sy) * 64;
            #pragma unroll
            for (int j = 0; j < 16; ++j) {
                int sx = col0 + j + kx - 1;
                float v = (rowok && sx >= 0 && sx < 64) ? xrow[sx] : 0.0f;
                Bsh[(nbase + j) * BKP + bk] = __float2bfloat16(v);
            }
        }
        __syncthreads();
        // ---- fragments + MFMA ----
        bf16x8 af[4], bfr[4];
        #pragma unroll
        for (int mi = 0; mi < 4; ++mi)
            af[mi] = *reinterpret_cast<const bf16x8*>(
                &Ash[(wm * 64 + mi * 16 + lr) * BKP + lq * 8]);
        #pragma unroll
        for (int ni = 0; ni < 4; ++ni)
            bfr[ni] = *reinterpret_cast<const bf16x8*>(
                &Bsh[(wn * 64 + ni * 16 + lr) * BKP + lq * 8]);
        #pragma unroll
        for (int mi = 0; mi < 4; ++mi)
            #pragma unroll
            for (int ni = 0; ni < 4; ++ni)
                acc[mi][ni] = __builtin_amdgcn_mfma_f32_16x16x32_bf16(
                    af[mi], bfr[ni], acc[mi][ni], 0, 0, 0);
        __syncthreads();
    }

    // ---- epilogue: D[row][col] with col=lane&15, row=(lane>>4)*4+v ----
    #pragma unroll
    for (int mi = 0; mi < 4; ++mi) {
        int oc = oc0 + wm * 64 + mi * 16 + lq * 4;
        #pragma unroll
        for (int ni = 0; ni < 4; ++ni) {
            int n = n0 + wn * 64 + ni * 16 + lr;
            #pragma unroll
            for (int v = 0; v < 4; ++v) {
                float r = acc[mi][ni][v] + bias[oc + v];
                out[((size_t)(b * OC + oc + v)) * HW + n] = r;
            }
        }
    }
}

extern "C" void kernel_launch(void* const* d_in, const int* in_sizes, int n_in,
                              void* d_out, int out_size, void* d_ws, size_t ws_size,
                              hipStream_t stream) {
    const float* x      = (const float*)d_in[0];  // [16,512,64,64]
    const float* style  = (const float*)d_in[1];  // [16,512]
    const float* weight = (const float*)d_in[2];  // [512,512,3,3]
    const float* bias   = (const float*)d_in[3];  // [512]
    const float* mod_w  = (const float*)d_in[4];  // [512,512]
    const float* mod_b  = (const float*)d_in[5];  // [512]
    float* out = (float*)d_out;

    // workspace: s [16*512 f32] @0, wmod bf16 [16*512*4608] @32KB
    float* s_ws = (float*)d_ws;
    __hip_bfloat16* wmod = (__hip_bfloat16*)((char*)d_ws + 16 * 512 * sizeof(float));

    style_mod_kernel<<<2048, 256, 0, stream>>>(style, mod_w, mod_b, s_ws);
    wmod_kernel<<<16 * 512, 256, 0, stream>>>(weight, s_ws, wmod);
    dim3 grid(HW / BN, OC / BM, 16);
    conv_kernel<<<grid, 256, 0, stream>>>(x, wmod, bias, out);
}

// Round 2
// 720.867 us; speedup vs baseline: 2.2565x; 2.2565x over previous
//
#include <hip/hip_runtime.h>
#include <hip/hip_bf16.h>

// ModulatedConv2d b=16, ic=oc=512, k=3, h=w=64.
// R2: tap-decomposed implicit GEMM. B operand read DIRECTLY from global
// channels-last bf16 xT[b][pix][ic] (zero row at pix=4096 for padding).
// A = wmod reordered [b][oc][tap*512+ic], staged in LDS (double-buffered regs).
// Kills the im2col LDS transpose that caused 3.2e8 bank conflicts (R1).

typedef __bf16 bf16x8 __attribute__((ext_vector_type(8)));
typedef float  f32x4  __attribute__((ext_vector_type(4)));

#define IC   512
#define OC   512
#define HW   4096
#define KTOT 4608
#define NITER 144   // 9 taps * 16 ic-chunks of 32

// ---------------- kernel 1: style modulation s[b][i] ----------------
__global__ __launch_bounds__(256) void style_mod_kernel(
    const float* __restrict__ style, const float* __restrict__ mod_w,
    const float* __restrict__ mod_b, float* __restrict__ s_out)
{
    int pair = blockIdx.x * 4 + (threadIdx.x >> 6);
    int lane = threadIdx.x & 63;
    int b = pair >> 9;
    int i = pair & 511;
    const float4* sv = (const float4*)(style + b * 512);
    const float4* wv = (const float4*)(mod_w + i * 512);
    float4 a0 = sv[lane * 2], a1 = sv[lane * 2 + 1];
    float4 w0 = wv[lane * 2], w1 = wv[lane * 2 + 1];
    float sum = a0.x*w0.x + a0.y*w0.y + a0.z*w0.z + a0.w*w0.w
              + a1.x*w1.x + a1.y*w1.y + a1.z*w1.z + a1.w*w1.w;
    #pragma unroll
    for (int off = 32; off; off >>= 1) sum += __shfl_xor(sum, off);
    if (lane == 0) s_out[pair] = sum + mod_b[i];
}

// ------------- kernel 2: demod + bf16 wmod, layout [b][oc][tap][ic] -------------
__global__ __launch_bounds__(256) void wmod_kernel(
    const float* __restrict__ weight,   // [512][512*9] (oc-major, e = ic*9+tap)
    const float* __restrict__ s_in,
    __hip_bfloat16* __restrict__ wmod)  // [16*512][4608] (e' = tap*512+ic)
{
    int b  = blockIdx.x >> 9;
    int oc = blockIdx.x & 511;
    __shared__ float s_sh[512];
    __shared__ float red[256];
    int t = threadIdx.x;
    s_sh[t]       = s_in[b * 512 + t];
    s_sh[t + 256] = s_in[b * 512 + t + 256];
    __syncthreads();
    const float* wrow = weight + (size_t)oc * KTOT;
    float partial = 0.f;
    for (int e = t; e < KTOT; e += 256) {      // coalesced reads, warms L1
        float v = wrow[e] * s_sh[e / 9];
        partial += v * v;
    }
    red[t] = partial;
    __syncthreads();
    #pragma unroll
    for (int off = 128; off; off >>= 1) {
        if (t < off) red[t] += red[t + off];
        __syncthreads();
    }
    float demod = rsqrtf(red[0] + 1e-8f);
    __hip_bfloat16* dst = wmod + (size_t)blockIdx.x * KTOT;
    for (int ep = t; ep < KTOT; ep += 256) {   // coalesced writes; reads hit L1
        int tap = ep >> 9, ic = ep & 511;
        dst[ep] = __float2bfloat16(wrow[ic * 9 + tap] * s_sh[ic] * demod);
    }
}

// ------------- kernel 3a: zero pad row of xT -------------
__global__ void zero_row_kernel(__hip_bfloat16* xT) {
    ((unsigned*)(xT + ((size_t)blockIdx.x * 4097 + 4096) * 512))[threadIdx.x] = 0u;
}

// ------------- kernel 3b: x [b][ic][pix] f32 -> xT [b][pix][ic] bf16 -------------
__global__ __launch_bounds__(256) void xpose_kernel(
    const float* __restrict__ x, __hip_bfloat16* __restrict__ xT)
{
    __shared__ __align__(16) float tile[64][68];
    int b = blockIdx.z, ic0 = blockIdx.y * 64, p0 = blockIdx.x * 64;
    int t = threadIdx.x;
    const float* xb = x + ((size_t)b * 512 + ic0) * 4096 + p0;
    int rr = t >> 4, cc = (t & 15) * 4;
    #pragma unroll
    for (int i = 0; i < 4; ++i) {
        float4 v = *(const float4*)(xb + (size_t)(rr + i * 16) * 4096 + cc);
        *(float4*)&tile[rr + i * 16][cc] = v;
    }
    __syncthreads();
    int pr = t >> 2, io = (t & 3) * 16;
    __hip_bfloat16 obuf[16];
    #pragma unroll
    for (int j = 0; j < 16; ++j) obuf[j] = __float2bfloat16(tile[io + j][pr]);
    __hip_bfloat16* dst = xT + ((size_t)b * 4097 + p0 + pr) * 512 + ic0 + io;
    *(uint4*)dst       = *(uint4*)&obuf[0];
    *(uint4*)(dst + 8) = *(uint4*)&obuf[8];
}

// ------------- kernel 4: conv as 9 accumulated GEMMs -------------
__global__ __launch_bounds__(256) void conv_kernel(
    const __hip_bfloat16* __restrict__ xT,    // [16][4097][512]
    const __hip_bfloat16* __restrict__ wmod,  // [16*512][4608]
    const float* __restrict__ bias,
    float* __restrict__ out)                  // [16][512][4096]
{
    __shared__ __align__(16) __hip_bfloat16 Ash[2][128 * 32];

    const int t    = threadIdx.x;
    const int lane = t & 63;
    const int wid  = t >> 6;
    const int wm   = wid >> 1;
    const int wn   = wid & 1;
    const int lr   = lane & 15;
    const int lq   = lane >> 4;

    // XCD-aware decode: per XCD: 2 b's, order b -> octile -> ntile (A panel L2-resident)
    int bid = blockIdx.x;
    int xcd = bid & 7, idx = bid >> 3;
    int nt  = idx & 31;
    int oc4 = (idx >> 5) & 3;
    int bb  = idx >> 7;
    int b   = xcd * 2 + bb;
    int oc0 = oc4 * 128, n0 = nt * 128;

    const __hip_bfloat16* wb = wmod + (size_t)(b * 512 + oc0) * KTOT;
    const __hip_bfloat16* xb = xT + (size_t)b * 4097 * 512;

    // A staging: thread t covers 16B units t and t+256 of the 8KB chunk
    const int ar0 = t >> 2;
    const int ak0 = (t & 3) * 8;

    f32x4 acc[4][4] = {};
    uint4 a0, a1;

#define LOAD_A(kk) { int tp = (kk) >> 4, i0 = ((kk) & 15) << 5; int kb = tp * 512 + i0; \
    a0 = *(const uint4*)(wb + (size_t)ar0 * KTOT + kb + ak0); \
    a1 = *(const uint4*)(wb + (size_t)(ar0 + 64) * KTOT + kb + ak0); }
#define WRITE_A(buf) { *(uint4*)(&Ash[buf][ar0 * 32 + ak0]) = a0; \
    *(uint4*)(&Ash[buf][(ar0 + 64) * 32 + ak0]) = a1; }

    LOAD_A(0); WRITE_A(0); LOAD_A(1);
    __syncthreads();

    for (int tap = 0; tap < 9; ++tap) {
        int dy = tap / 3 - 1, dx = tap % 3 - 1;
        // per-lane B base pointers for this tap (pixel shifted by (dy,dx); OOB -> zero row)
        const __hip_bfloat16* bptr[4];
        #pragma unroll
        for (int ni = 0; ni < 4; ++ni) {
            int p  = n0 + wn * 64 + ni * 16 + lr;
            int sy = (p >> 6) + dy;
            int sx = (p & 63) + dx;
            bool ok = (sy >= 0) & (sy < 64) & (sx >= 0) & (sx < 64);
            int pix = ok ? ((sy << 6) + sx) : 4096;
            bptr[ni] = xb + (size_t)pix * 512 + lq * 8;
        }
        for (int i16 = 0; i16 < 16; ++i16) {
            int kk  = tap * 16 + i16;
            int cur = kk & 1;
            WRITE_A(cur ^ 1);                 // regs hold A(kk+1)
            if (kk + 2 < NITER) LOAD_A(kk + 2);
            int icoff = i16 * 32;
            bf16x8 bfr[4];
            #pragma unroll
            for (int ni = 0; ni < 4; ++ni)
                bfr[ni] = *(const bf16x8*)(bptr[ni] + icoff);
            bf16x8 af[4];
            #pragma unroll
            for (int mi = 0; mi < 4; ++mi)
                af[mi] = *(const bf16x8*)(&Ash[cur][(wm * 64 + mi * 16 + lr) * 32 + lq * 8]);
            #pragma unroll
            for (int mi = 0; mi < 4; ++mi)
                #pragma unroll
                for (int ni = 0; ni < 4; ++ni)
                    acc[mi][ni] = __builtin_amdgcn_mfma_f32_16x16x32_bf16(
                        af[mi], bfr[ni], acc[mi][ni], 0, 0, 0);
            __syncthreads();
        }
    }
#undef LOAD_A
#undef WRITE_A

    #pragma unroll
    for (int mi = 0; mi < 4; ++mi) {
        int oc = oc0 + wm * 64 + mi * 16 + lq * 4;
        #pragma unroll
        for (int ni = 0; ni < 4; ++ni) {
            int n = n0 + wn * 64 + ni * 16 + lr;
            #pragma unroll
            for (int v = 0; v < 4; ++v) {
                float r = acc[mi][ni][v] + bias[oc + v];
                out[((size_t)(b * OC + oc + v)) * HW + n] = r;
            }
        }
    }
}

extern "C" void kernel_launch(void* const* d_in, const int* in_sizes, int n_in,
                              void* d_out, int out_size, void* d_ws, size_t ws_size,
                              hipStream_t stream) {
    const float* x      = (const float*)d_in[0];
    const float* style  = (const float*)d_in[1];
    const float* weight = (const float*)d_in[2];
    const float* bias   = (const float*)d_in[3];
    const float* mod_w  = (const float*)d_in[4];
    const float* mod_b  = (const float*)d_in[5];
    float* out = (float*)d_out;

    // ws: s [32KB] | wmod bf16 [16*512*4608 = 75.5MB] | xT bf16 [16*4097*512 = 67.2MB]
    float* s_ws = (float*)d_ws;
    __hip_bfloat16* wmod = (__hip_bfloat16*)((char*)d_ws + 32768);
    __hip_bfloat16* xT   = (__hip_bfloat16*)((char*)d_ws + 32768 + (size_t)16 * 512 * KTOT * 2);

    style_mod_kernel<<<2048, 256, 0, stream>>>(style, mod_w, mod_b, s_ws);
    wmod_kernel<<<16 * 512, 256, 0, stream>>>(weight, s_ws, wmod);
    zero_row_kernel<<<16, 256, 0, stream>>>(xT);
    dim3 tgrid(64, 8, 16);
    xpose_kernel<<<tgrid, 256, 0, stream>>>(x, xT);
    conv_kernel<<<2048, 256, 0, stream>>>(xT, wmod, bias, out);
}

// Round 3
// 525.000 us; speedup vs baseline: 3.0984x; 1.3731x over previous
//
#include <hip/hip_runtime.h>
#include <hip/hip_bf16.h>

// ModulatedConv2d b=16, ic=oc=512, k=3, h=w=64.
// R3: m97-structure implicit GEMM. Both A (wmod) and B (im2col from xT) staged
// to LDS via global_load_lds(16B), double-buffered, stage(k+1) issued before
// compute(k), one barrier per K-step. Tap-decomposed K = 9 taps x 16 ic-chunks.

typedef __bf16 bf16x8 __attribute__((ext_vector_type(8)));
typedef float  f32x4  __attribute__((ext_vector_type(4)));

#define IC   512
#define OC   512
#define HW   4096
#define KTOT 4608
#define NK   144    // 9 taps * 16 chunks of 32

typedef __attribute__((address_space(3))) unsigned lds_u32;
typedef const __attribute__((address_space(1))) unsigned glb_u32;
#define GLL16(gsrc, ldst) \
    __builtin_amdgcn_global_load_lds((glb_u32*)(gsrc), (lds_u32*)(ldst), 16, 0, 0)

// ---------------- kernel 1: style modulation s[b][i] ----------------
__global__ __launch_bounds__(256) void style_mod_kernel(
    const float* __restrict__ style, const float* __restrict__ mod_w,
    const float* __restrict__ mod_b, float* __restrict__ s_out)
{
    int pair = blockIdx.x * 4 + (threadIdx.x >> 6);
    int lane = threadIdx.x & 63;
    int b = pair >> 9;
    int i = pair & 511;
    const float4* sv = (const float4*)(style + b * 512);
    const float4* wv = (const float4*)(mod_w + i * 512);
    float4 a0 = sv[lane * 2], a1 = sv[lane * 2 + 1];
    float4 w0 = wv[lane * 2], w1 = wv[lane * 2 + 1];
    float sum = a0.x*w0.x + a0.y*w0.y + a0.z*w0.z + a0.w*w0.w
              + a1.x*w1.x + a1.y*w1.y + a1.z*w1.z + a1.w*w1.w;
    #pragma unroll
    for (int off = 32; off; off >>= 1) sum += __shfl_xor(sum, off);
    if (lane == 0) s_out[pair] = sum + mod_b[i];
}

// ------------- kernel 2: demod + bf16 wmod, layout [b][oc][tap*512+ic] -------------
__global__ __launch_bounds__(256) void wmod_kernel(
    const float* __restrict__ weight,   // [512][4608] (e = ic*9+tap)
    const float* __restrict__ s_in,
    __hip_bfloat16* __restrict__ wmod)  // [16*512][4608] (e' = tap*512+ic)
{
    int b  = blockIdx.x >> 9;
    int oc = blockIdx.x & 511;
    __shared__ float s_sh[512];
    __shared__ float red[256];
    int t = threadIdx.x;
    s_sh[t]       = s_in[b * 512 + t];
    s_sh[t + 256] = s_in[b * 512 + t + 256];
    __syncthreads();
    const float* wrow = weight + (size_t)oc * KTOT;
    float partial = 0.f;
    for (int e = t; e < KTOT; e += 256) {
        float v = wrow[e] * s_sh[e / 9];
        partial += v * v;
    }
    red[t] = partial;
    __syncthreads();
    #pragma unroll
    for (int off = 128; off; off >>= 1) {
        if (t < off) red[t] += red[t + off];
        __syncthreads();
    }
    float demod = rsqrtf(red[0] + 1e-8f);
    __hip_bfloat16* dst = wmod + (size_t)blockIdx.x * KTOT;
    for (int ep = t; ep < KTOT; ep += 256) {
        int tap = ep >> 9, ic = ep & 511;
        dst[ep] = __float2bfloat16(wrow[ic * 9 + tap] * s_sh[ic] * demod);
    }
}

// ------------- kernel 3a: zero pad row of xT -------------
__global__ void zero_row_kernel(__hip_bfloat16* xT) {
    ((unsigned*)(xT + ((size_t)blockIdx.x * 4097 + 4096) * 512))[threadIdx.x] = 0u;
}

// ------------- kernel 3b: x [b][ic][pix] f32 -> xT [b][pix][ic] bf16 -------------
__global__ __launch_bounds__(256) void xpose_kernel(
    const float* __restrict__ x, __hip_bfloat16* __restrict__ xT)
{
    __shared__ __align__(16) float tile[64][68];
    int b = blockIdx.z, ic0 = blockIdx.y * 64, p0 = blockIdx.x * 64;
    int t = threadIdx.x;
    const float* xb = x + ((size_t)b * 512 + ic0) * 4096 + p0;
    int rr = t >> 4, cc = (t & 15) * 4;
    #pragma unroll
    for (int i = 0; i < 4; ++i) {
        float4 v = *(const float4*)(xb + (size_t)(rr + i * 16) * 4096 + cc);
        *(float4*)&tile[rr + i * 16][cc] = v;
    }
    __syncthreads();
    int pr = t >> 2, io = (t & 3) * 16;
    __hip_bfloat16 obuf[16];
    #pragma unroll
    for (int j = 0; j < 16; ++j) obuf[j] = __float2bfloat16(tile[io + j][pr]);
    __hip_bfloat16* dst = xT + ((size_t)b * 4097 + p0 + pr) * 512 + ic0 + io;
    *(uint4*)dst       = *(uint4*)&obuf[0];
    *(uint4*)(dst + 8) = *(uint4*)&obuf[8];
}

// ------------- kernel 4: conv, m97 structure -------------
__global__ __launch_bounds__(256) void conv_kernel(
    const __hip_bfloat16* __restrict__ xT,    // [16][4097][512]
    const __hip_bfloat16* __restrict__ wmod,  // [16*512][4608]
    const float* __restrict__ bias,
    float* __restrict__ out)                  // [16][512][4096]
{
    __shared__ __align__(16) __hip_bfloat16 Ash[2][128 * 32];
    __shared__ __align__(16) __hip_bfloat16 Bsh[2][128 * 32];

    const int t    = threadIdx.x;
    const int lane = t & 63;
    const int wid  = t >> 6;
    const int wm   = wid >> 1;
    const int wn   = wid & 1;
    const int lr   = lane & 15;
    const int lq   = lane >> 4;

    // block decode: per XCD 2 b's; ntile outer, octile INNER (4 consecutive
    // blocks share one B panel -> L2 reuse)
    int bid = blockIdx.x;
    int xcd = bid & 7, idx = bid >> 3;
    int oc4 = idx & 3;
    int nt  = (idx >> 2) & 31;
    int bb  = idx >> 7;
    int b   = xcd * 2 + bb;
    int oc0 = oc4 * 128, n0 = nt * 128;

    const __hip_bfloat16* wb = wmod + (size_t)(b * 512 + oc0) * KTOT;
    const __hip_bfloat16* xb = xT + (size_t)b * 4097 * 512;

    // staging geometry: 16B unit u covers (row u>>2, quad u&3); thread t owns
    // units t (rows 0..63) and t+256 (rows 64..127). LDS dest = linear u*16B.
    const int quad8 = (t & 3) * 8;                 // element offset within row
    const __hip_bfloat16* gA0 = wb + (size_t)(t >> 2) * KTOT + quad8;
    const __hip_bfloat16* gA1 = gA0 + (size_t)64 * KTOT;
    // B pixel coords for unit rows: p0 = n0 + (t>>2) (y row n0>>6), p1 = p0+64
    const int ypx = (n0 + (t >> 2)) >> 6;
    const int xpx = (n0 + (t >> 2)) & 63;

    f32x4 acc[4][4] = {};

#define STAGE(buf, kk) { \
    int tap = (kk) >> 4, ch = (kk) & 15; \
    int dy = tap / 3 - 1, dx = tap - (tap / 3) * 3 - 1; \
    int acol = tap * 512 + ch * 32; \
    GLL16(gA0 + acol, &Ash[buf][t * 8]); \
    GLL16(gA1 + acol, &Ash[buf][(t + 256) * 8]); \
    int sy = ypx + dy, sx = xpx + dx; \
    int ok0 = ((unsigned)sy < 64u) & ((unsigned)sx < 64u); \
    int pix0 = ok0 ? ((sy << 6) + sx) : 4096; \
    int sy1 = sy + 1; \
    int ok1 = ((unsigned)sy1 < 64u) & ((unsigned)sx < 64u); \
    int pix1 = ok1 ? ((sy1 << 6) + sx) : 4096; \
    int bcol = ch * 32 + quad8; \
    GLL16(xb + (size_t)pix0 * 512 + bcol, &Bsh[buf][t * 8]); \
    GLL16(xb + (size_t)pix1 * 512 + bcol, &Bsh[buf][(t + 256) * 8]); \
}

    STAGE(0, 0);
    __syncthreads();

    int cur = 0;
    for (int kk = 0; kk < NK; ++kk) {
        if (kk + 1 < NK) STAGE(cur ^ 1, kk + 1);
        bf16x8 af[4], bfr[4];
        #pragma unroll
        for (int mi = 0; mi < 4; ++mi)
            af[mi] = *(const bf16x8*)(&Ash[cur][(wm * 64 + mi * 16 + lr) * 32 + lq * 8]);
        #pragma unroll
        for (int ni = 0; ni < 4; ++ni)
            bfr[ni] = *(const bf16x8*)(&Bsh[cur][(wn * 64 + ni * 16 + lr) * 32 + lq * 8]);
        #pragma unroll
        for (int mi = 0; mi < 4; ++mi)
            #pragma unroll
            for (int ni = 0; ni < 4; ++ni)
                acc[mi][ni] = __builtin_amdgcn_mfma_f32_16x16x32_bf16(
                    af[mi], bfr[ni], acc[mi][ni], 0, 0, 0);
        __syncthreads();
        cur ^= 1;
    }
#undef STAGE

    #pragma unroll
    for (int mi = 0; mi < 4; ++mi) {
        int oc = oc0 + wm * 64 + mi * 16 + lq * 4;
        #pragma unroll
        for (int ni = 0; ni < 4; ++ni) {
            int n = n0 + wn * 64 + ni * 16 + lr;
            #pragma unroll
            for (int v = 0; v < 4; ++v) {
                float r = acc[mi][ni][v] + bias[oc + v];
                out[((size_t)(b * OC + oc + v)) * HW + n] = r;
            }
        }
    }
}

extern "C" void kernel_launch(void* const* d_in, const int* in_sizes, int n_in,
                              void* d_out, int out_size, void* d_ws, size_t ws_size,
                              hipStream_t stream) {
    const float* x      = (const float*)d_in[0];
    const float* style  = (const float*)d_in[1];
    const float* weight = (const float*)d_in[2];
    const float* bias   = (const float*)d_in[3];
    const float* mod_w  = (const float*)d_in[4];
    const float* mod_b  = (const float*)d_in[5];
    float* out = (float*)d_out;

    // ws: s [32KB] | wmod bf16 [75.5MB] | xT bf16 [67.2MB]
    float* s_ws = (float*)d_ws;
    __hip_bfloat16* wmod = (__hip_bfloat16*)((char*)d_ws + 32768);
    __hip_bfloat16* xT   = (__hip_bfloat16*)((char*)d_ws + 32768 + (size_t)16 * 512 * KTOT * 2);

    style_mod_kernel<<<2048, 256, 0, stream>>>(style, mod_w, mod_b, s_ws);
    wmod_kernel<<<16 * 512, 256, 0, stream>>>(weight, s_ws, wmod);
    zero_row_kernel<<<16, 256, 0, stream>>>(xT);
    dim3 tgrid(64, 8, 16);
    xpose_kernel<<<tgrid, 256, 0, stream>>>(x, xT);
    conv_kernel<<<2048, 256, 0, stream>>>(xT, wmod, bias, out);
}

// Round 4
// 521.544 us; speedup vs baseline: 3.1189x; 1.0066x over previous
//
#include <hip/hip_runtime.h>
#include <hip/hip_bf16.h>

// ModulatedConv2d b=16, ic=oc=512, k=3, h=w=64.
// R4: m97-structure implicit GEMM with HOISTED im2col addressing.
// tap outer (9) x ch inner (16, fully unrolled): B pixel pointers computed
// once per tap; all inner-loop staged-load addresses are base + compile-time
// offset (folds into the instruction offset field -> ~zero addr VALU/iter).

typedef __bf16 bf16x8 __attribute__((ext_vector_type(8)));
typedef float  f32x4  __attribute__((ext_vector_type(4)));

#define IC   512
#define OC   512
#define HW   4096
#define KTOT 4608

typedef __attribute__((address_space(3))) unsigned lds_u32;
typedef const __attribute__((address_space(1))) unsigned glb_u32;
#define GLL16(gsrc, ldst) \
    __builtin_amdgcn_global_load_lds((glb_u32*)(gsrc), (lds_u32*)(ldst), 16, 0, 0)

// ---------------- kernel 1: style modulation s[b][i] ----------------
__global__ __launch_bounds__(256) void style_mod_kernel(
    const float* __restrict__ style, const float* __restrict__ mod_w,
    const float* __restrict__ mod_b, float* __restrict__ s_out)
{
    int pair = blockIdx.x * 4 + (threadIdx.x >> 6);
    int lane = threadIdx.x & 63;
    int b = pair >> 9;
    int i = pair & 511;
    const float4* sv = (const float4*)(style + b * 512);
    const float4* wv = (const float4*)(mod_w + i * 512);
    float4 a0 = sv[lane * 2], a1 = sv[lane * 2 + 1];
    float4 w0 = wv[lane * 2], w1 = wv[lane * 2 + 1];
    float sum = a0.x*w0.x + a0.y*w0.y + a0.z*w0.z + a0.w*w0.w
              + a1.x*w1.x + a1.y*w1.y + a1.z*w1.z + a1.w*w1.w;
    #pragma unroll
    for (int off = 32; off; off >>= 1) sum += __shfl_xor(sum, off);
    if (lane == 0) s_out[pair] = sum + mod_b[i];
}

// ------------- kernel 2: demod + bf16 wmod, layout [b][oc][tap*512+ic] -------------
__global__ __launch_bounds__(256) void wmod_kernel(
    const float* __restrict__ weight,   // [512][4608] (e = ic*9+tap)
    const float* __restrict__ s_in,
    __hip_bfloat16* __restrict__ wmod)  // [16*512][4608] (e' = tap*512+ic)
{
    int b  = blockIdx.x >> 9;
    int oc = blockIdx.x & 511;
    __shared__ float s_sh[512];
    __shared__ float red[256];
    int t = threadIdx.x;
    s_sh[t]       = s_in[b * 512 + t];
    s_sh[t + 256] = s_in[b * 512 + t + 256];
    __syncthreads();
    const float* wrow = weight + (size_t)oc * KTOT;
    float partial = 0.f;
    for (int e = t; e < KTOT; e += 256) {
        float v = wrow[e] * s_sh[e / 9];
        partial += v * v;
    }
    red[t] = partial;
    __syncthreads();
    #pragma unroll
    for (int off = 128; off; off >>= 1) {
        if (t < off) red[t] += red[t + off];
        __syncthreads();
    }
    float demod = rsqrtf(red[0] + 1e-8f);
    __hip_bfloat16* dst = wmod + (size_t)blockIdx.x * KTOT;
    for (int ep = t; ep < KTOT; ep += 256) {
        int tap = ep >> 9, ic = ep & 511;
        dst[ep] = __float2bfloat16(wrow[ic * 9 + tap] * s_sh[ic] * demod);
    }
}

// ------------- kernel 3a: zero pad row of xT -------------
__global__ void zero_row_kernel(__hip_bfloat16* xT) {
    ((unsigned*)(xT + ((size_t)blockIdx.x * 4097 + 4096) * 512))[threadIdx.x] = 0u;
}

// ------------- kernel 3b: x [b][ic][pix] f32 -> xT [b][pix][ic] bf16 -------------
__global__ __launch_bounds__(256) void xpose_kernel(
    const float* __restrict__ x, __hip_bfloat16* __restrict__ xT)
{
    __shared__ __align__(16) float tile[64][68];
    int b = blockIdx.z, ic0 = blockIdx.y * 64, p0 = blockIdx.x * 64;
    int t = threadIdx.x;
    const float* xb = x + ((size_t)b * 512 + ic0) * 4096 + p0;
    int rr = t >> 4, cc = (t & 15) * 4;
    #pragma unroll
    for (int i = 0; i < 4; ++i) {
        float4 v = *(const float4*)(xb + (size_t)(rr + i * 16) * 4096 + cc);
        *(float4*)&tile[rr + i * 16][cc] = v;
    }
    __syncthreads();
    int pr = t >> 2, io = (t & 3) * 16;
    __hip_bfloat16 obuf[16];
    #pragma unroll
    for (int j = 0; j < 16; ++j) obuf[j] = __float2bfloat16(tile[io + j][pr]);
    __hip_bfloat16* dst = xT + ((size_t)b * 4097 + p0 + pr) * 512 + ic0 + io;
    *(uint4*)dst       = *(uint4*)&obuf[0];
    *(uint4*)(dst + 8) = *(uint4*)&obuf[8];
}

// ------------- kernel 4: conv, m97 structure + hoisted addressing -------------
__global__ __launch_bounds__(256) void conv_kernel(
    const __hip_bfloat16* __restrict__ xT,    // [16][4097][512]
    const __hip_bfloat16* __restrict__ wmod,  // [16*512][4608]
    const float* __restrict__ bias,
    float* __restrict__ out)                  // [16][512][4096]
{
    __shared__ __align__(16) __hip_bfloat16 Ash[2][128 * 32];
    __shared__ __align__(16) __hip_bfloat16 Bsh[2][128 * 32];

    const int t    = threadIdx.x;
    const int lane = t & 63;
    const int wid  = t >> 6;
    const int wm   = wid >> 1;
    const int wn   = wid & 1;
    const int lr   = lane & 15;
    const int lq   = lane >> 4;

    // block decode: per XCD 2 b's; octile inner (4 consecutive blocks share B panel)
    int bid = blockIdx.x;
    int xcd = bid & 7, idx = bid >> 3;
    int oc4 = idx & 3;
    int nt  = (idx >> 2) & 31;
    int bb  = idx >> 7;
    int b   = xcd * 2 + bb;
    int oc0 = oc4 * 128, n0 = nt * 128;

    const __hip_bfloat16* wb = wmod + (size_t)(b * 512 + oc0) * KTOT;
    const __hip_bfloat16* xb = xT + (size_t)b * 4097 * 512;

    // staging geometry: 16B unit u -> (row u>>2, quad u&3); thread t owns units
    // t (rows 0..63) and t+256 (rows 64..127); LDS dest = linear u*16B.
    const int quad8 = (t & 3) * 8;
    const int srow  = t >> 2;
    const int ypx   = (n0 + srow) >> 6;
    const int xpx   = (n0 + srow) & 63;

    const __hip_bfloat16* pA0 = wb + (size_t)srow * KTOT + quad8;
    const __hip_bfloat16* pA1 = pA0 + (size_t)64 * KTOT;

    __hip_bfloat16* const dA0_0 = &Ash[0][t * 8];
    __hip_bfloat16* const dA0_1 = &Ash[1][t * 8];
    __hip_bfloat16* const dA1_0 = &Ash[0][(t + 256) * 8];
    __hip_bfloat16* const dA1_1 = &Ash[1][(t + 256) * 8];
    __hip_bfloat16* const dB0_0 = &Bsh[0][t * 8];
    __hip_bfloat16* const dB0_1 = &Bsh[1][t * 8];
    __hip_bfloat16* const dB1_0 = &Bsh[0][(t + 256) * 8];
    __hip_bfloat16* const dB1_1 = &Bsh[1][(t + 256) * 8];

    f32x4 acc[4][4] = {};

// per-tap B row pointers (pixel shifted by (dy,dx); OOB -> zero row 4096)
#define BPTRS(tap, P0, P1) { \
    int dy = (tap) / 3 - 1, dx = (tap) % 3 - 1; \
    int sy = ypx + dy, sx = xpx + dx; \
    int pix0 = ((((unsigned)sy) < 64u) & (((unsigned)sx) < 64u)) ? ((sy << 6) + sx) : 4096; \
    int sy1 = sy + 1; \
    int pix1 = ((((unsigned)sy1) < 64u) & (((unsigned)sx) < 64u)) ? ((sy1 << 6) + sx) : 4096; \
    P0 = xb + (size_t)pix0 * 512 + quad8; \
    P1 = xb + (size_t)pix1 * 512 + quad8; }

// stage one K-chunk: A from pA0/pA1 + AOFF elems, B from BS0/BS1 + BOFF elems,
// into buffer SB (compile-time) — addresses fold to base + imm offset.
#define STAGE_CH(AOFF, BS0, BS1, BOFF, SB) { \
    GLL16(pA0 + (AOFF), (SB) ? dA0_1 : dA0_0); \
    GLL16(pA1 + (AOFF), (SB) ? dA1_1 : dA1_0); \
    GLL16((BS0) + (BOFF), (SB) ? dB0_1 : dB0_0); \
    GLL16((BS1) + (BOFF), (SB) ? dB1_1 : dB1_0); }

#define COMPUTE(CB) { \
    bf16x8 af[4], bfr[4]; \
    _Pragma("unroll") for (int mi = 0; mi < 4; ++mi) \
        af[mi] = *(const bf16x8*)(&Ash[CB][(wm * 64 + mi * 16 + lr) * 32 + lq * 8]); \
    _Pragma("unroll") for (int ni = 0; ni < 4; ++ni) \
        bfr[ni] = *(const bf16x8*)(&Bsh[CB][(wn * 64 + ni * 16 + lr) * 32 + lq * 8]); \
    _Pragma("unroll") for (int mi = 0; mi < 4; ++mi) \
        _Pragma("unroll") for (int ni = 0; ni < 4; ++ni) \
            acc[mi][ni] = __builtin_amdgcn_mfma_f32_16x16x32_bf16( \
                af[mi], bfr[ni], acc[mi][ni], 0, 0, 0); }

    const __hip_bfloat16 *pB0, *pB1, *nB0, *nB1;
    BPTRS(0, pB0, pB1);
    STAGE_CH(0, pB0, pB1, 0, 0);      // stage kk=0 into buf0
    __syncthreads();

    for (int tap = 0; tap < 9; ++tap) {
        const bool last = (tap == 8);
        BPTRS(tap + 1, nB0, nB1);     // next tap's B bases (unused when last)
        #pragma unroll
        for (int ch = 0; ch < 16; ++ch) {
            const int sb = (ch + 1) & 1, cb = ch & 1;
            if (ch < 15) {
                STAGE_CH((ch + 1) * 32, pB0, pB1, (ch + 1) * 32, sb);
            } else if (!last) {
                STAGE_CH(512, nB0, nB1, 0, sb);
            }
            COMPUTE(cb);
            __syncthreads();
        }
        pA0 += 512; pA1 += 512;
        pB0 = nB0; pB1 = nB1;
    }
#undef BPTRS
#undef STAGE_CH
#undef COMPUTE

    #pragma unroll
    for (int mi = 0; mi < 4; ++mi) {
        int oc = oc0 + wm * 64 + mi * 16 + lq * 4;
        #pragma unroll
        for (int ni = 0; ni < 4; ++ni) {
            int n = n0 + wn * 64 + ni * 16 + lr;
            #pragma unroll
            for (int v = 0; v < 4; ++v) {
                float r = acc[mi][ni][v] + bias[oc + v];
                out[((size_t)(b * OC + oc + v)) * HW + n] = r;
            }
        }
    }
}

extern "C" void kernel_launch(void* const* d_in, const int* in_sizes, int n_in,
                              void* d_out, int out_size, void* d_ws, size_t ws_size,
                              hipStream_t stream) {
    const float* x      = (const float*)d_in[0];
    const float* style  = (const float*)d_in[1];
    const float* weight = (const float*)d_in[2];
    const float* bias   = (const float*)d_in[3];
    const float* mod_w  = (const float*)d_in[4];
    const float* mod_b  = (const float*)d_in[5];
    float* out = (float*)d_out;

    // ws: s [32KB] | wmod bf16 [75.5MB] | xT bf16 [67.2MB]
    float* s_ws = (float*)d_ws;
    __hip_bfloat16* wmod = (__hip_bfloat16*)((char*)d_ws + 32768);
    __hip_bfloat16* xT   = (__hip_bfloat16*)((char*)d_ws + 32768 + (size_t)16 * 512 * KTOT * 2);

    style_mod_kernel<<<2048, 256, 0, stream>>>(style, mod_w, mod_b, s_ws);
    wmod_kernel<<<16 * 512, 256, 0, stream>>>(weight, s_ws, wmod);
    zero_row_kernel<<<16, 256, 0, stream>>>(xT);
    dim3 tgrid(64, 8, 16);
    xpose_kernel<<<tgrid, 256, 0, stream>>>(x, xT);
    conv_kernel<<<2048, 256, 0, stream>>>(xT, wmod, bias, out);
}

// Round 5
// 379.399 us; speedup vs baseline: 4.2875x; 1.3747x over previous
//
#include <hip/hip_runtime.h>
#include <hip/hip_bf16.h>

// ModulatedConv2d b=16, ic=oc=512, k=3, h=w=64.
// R5: 256x256 tile, BK=32, depth-4 LDS ring, counted vmcnt(8) (T3/T4),
// involution LDS swizzle via pre-swizzled global source (T2, rule 21),
// setprio around MFMA (T5). K = 9 taps x 16 ic-chunks = 144 chunks.

typedef __bf16 bf16x8 __attribute__((ext_vector_type(8)));
typedef float  f32x4  __attribute__((ext_vector_type(4)));

#define IC   512
#define OC   512
#define HW   4096
#define KTOT 4608

typedef __attribute__((address_space(3))) unsigned lds_u32;
typedef const __attribute__((address_space(1))) unsigned glb_u32;
#define GLL16(gsrc, ldst) \
    __builtin_amdgcn_global_load_lds((glb_u32*)(gsrc), (lds_u32*)(ldst), 16, 0, 0)
#define VMW(N) asm volatile("s_waitcnt vmcnt(" #N ")" ::: "memory")
#define BAR()  asm volatile("s_barrier" ::: "memory")

// ---------------- kernel 1: style modulation s[b][i] ----------------
__global__ __launch_bounds__(256) void style_mod_kernel(
    const float* __restrict__ style, const float* __restrict__ mod_w,
    const float* __restrict__ mod_b, float* __restrict__ s_out)
{
    int pair = blockIdx.x * 4 + (threadIdx.x >> 6);
    int lane = threadIdx.x & 63;
    int b = pair >> 9;
    int i = pair & 511;
    const float4* sv = (const float4*)(style + b * 512);
    const float4* wv = (const float4*)(mod_w + i * 512);
    float4 a0 = sv[lane * 2], a1 = sv[lane * 2 + 1];
    float4 w0 = wv[lane * 2], w1 = wv[lane * 2 + 1];
    float sum = a0.x*w0.x + a0.y*w0.y + a0.z*w0.z + a0.w*w0.w
              + a1.x*w1.x + a1.y*w1.y + a1.z*w1.z + a1.w*w1.w;
    #pragma unroll
    for (int off = 32; off; off >>= 1) sum += __shfl_xor(sum, off);
    if (lane == 0) s_out[pair] = sum + mod_b[i];
}

// ------------- kernel 2: demod + bf16 wmod, layout [b][oc][tap*512+ic] -------------
__global__ __launch_bounds__(256) void wmod_kernel(
    const float* __restrict__ weight,   // [512][4608] (e = ic*9+tap)
    const float* __restrict__ s_in,
    __hip_bfloat16* __restrict__ wmod)  // [16*512][4608] (e' = tap*512+ic)
{
    int b  = blockIdx.x >> 9;
    int oc = blockIdx.x & 511;
    __shared__ float s_sh[512];
    __shared__ float red[256];
    int t = threadIdx.x;
    s_sh[t]       = s_in[b * 512 + t];
    s_sh[t + 256] = s_in[b * 512 + t + 256];
    __syncthreads();
    const float* wrow = weight + (size_t)oc * KTOT;
    float partial = 0.f;
    for (int e = t; e < KTOT; e += 256) {
        float v = wrow[e] * s_sh[e / 9];
        partial += v * v;
    }
    red[t] = partial;
    __syncthreads();
    #pragma unroll
    for (int off = 128; off; off >>= 1) {
        if (t < off) red[t] += red[t + off];
        __syncthreads();
    }
    float demod = rsqrtf(red[0] + 1e-8f);
    __hip_bfloat16* dst = wmod + (size_t)blockIdx.x * KTOT;
    for (int ep = t; ep < KTOT; ep += 256) {
        int tap = ep >> 9, ic = ep & 511;
        dst[ep] = __float2bfloat16(wrow[ic * 9 + tap] * s_sh[ic] * demod);
    }
}

// ------------- kernel 3a: zero pad row of xT -------------
__global__ void zero_row_kernel(__hip_bfloat16* xT) {
    ((unsigned*)(xT + ((size_t)blockIdx.x * 4097 + 4096) * 512))[threadIdx.x] = 0u;
}

// ------------- kernel 3b: x [b][ic][pix] f32 -> xT [b][pix][ic] bf16 -------------
__global__ __launch_bounds__(256) void xpose_kernel(
    const float* __restrict__ x, __hip_bfloat16* __restrict__ xT)
{
    __shared__ __align__(16) float tile[64][68];
    int b = blockIdx.z, ic0 = blockIdx.y * 64, p0 = blockIdx.x * 64;
    int t = threadIdx.x;
    const float* xb = x + ((size_t)b * 512 + ic0) * 4096 + p0;
    int rr = t >> 4, cc = (t & 15) * 4;
    #pragma unroll
    for (int i = 0; i < 4; ++i) {
        float4 v = *(const float4*)(xb + (size_t)(rr + i * 16) * 4096 + cc);
        *(float4*)&tile[rr + i * 16][cc] = v;
    }
    __syncthreads();
    int pr = t >> 2, io = (t & 3) * 16;
    __hip_bfloat16 obuf[16];
    #pragma unroll
    for (int j = 0; j < 16; ++j) obuf[j] = __float2bfloat16(tile[io + j][pr]);
    __hip_bfloat16* dst = xT + ((size_t)b * 4097 + p0 + pr) * 512 + ic0 + io;
    *(uint4*)dst       = *(uint4*)&obuf[0];
    *(uint4*)(dst + 8) = *(uint4*)&obuf[8];
}

// ------------- kernel 4: conv, 256x256 ring-4 counted-vmcnt pipeline -------------
__global__ __launch_bounds__(512, 2) void conv_kernel(
    const __hip_bfloat16* __restrict__ xT,    // [16][4097][512]
    const __hip_bfloat16* __restrict__ wmod,  // [16*512][4608]
    const float* __restrict__ bias,
    float* __restrict__ out)                  // [16][512][4096]
{
    // ring of 4 K-tiles: A [256 oc][32 k], B [256 px][32 k], 16KB each
    __shared__ __align__(16) __hip_bfloat16 Ash[4][256 * 32];
    __shared__ __align__(16) __hip_bfloat16 Bsh[4][256 * 32];

    const int t    = threadIdx.x;
    const int lane = t & 63;
    const int wid  = t >> 6;      // 0..7
    const int wm   = wid >> 2;    // 0..1 (M half)
    const int wn   = wid & 3;     // 0..3 (N quarter)
    const int lr   = lane & 15;
    const int lq   = lane >> 4;

    // block decode: 512 blocks; per XCD 2 b's; oc-tile inner (B-panel L2 reuse)
    int bid = blockIdx.x;
    int xcd = bid & 7, idx = bid >> 3;
    int oc1 = idx & 1;
    int nt  = (idx >> 1) & 15;
    int bb  = (idx >> 5) & 1;
    int b   = xcd * 2 + bb;
    int oc0 = oc1 * 256, n0 = nt * 256;

    const __hip_bfloat16* wb = wmod + (size_t)(b * 512 + oc0) * KTOT;
    const __hip_bfloat16* xb = xT + (size_t)b * 4097 * 512;

    // stage geometry: slot u (thread t -> u=t and u=t+512): row u>>2, quad u&3.
    // involution swizzle: slot holds global quad q = (u&3) ^ ((u>>3)&3); since
    // (t+512)>>3 == t>>3 (mod 4), one per-thread quad offset serves both slots.
    const int qoff = (((t & 3) ^ ((t >> 3) & 3)) * 8);
    const int srow = t >> 2;                 // 0..127 (second slot: +128)
    const int p0g  = n0 + srow;
    const int y0p  = p0g >> 6, x0p = p0g & 63;

    const __hip_bfloat16* pA0 = wb + (size_t)srow * KTOT + qoff;
    const __hip_bfloat16* pA1 = pA0 + (size_t)128 * KTOT;

    // fragment-read bases (swizzled quad): row = 16*aligned + lr
    const int swq = (lq ^ ((lr >> 1) & 3)) * 8;
    const int arb = (wm * 128 + lr) * 32 + swq;
    const int brb = (wn * 64  + lr) * 32 + swq;

    f32x4 acc[8][4] = {};

    // per-tap B row pointers (pixel shifted by (dy,dx); OOB -> zero row 4096)
    auto bptrs = [&](int tap, const __hip_bfloat16*& P0, const __hip_bfloat16*& P1) {
        int dy = tap / 3 - 1, dx = tap % 3 - 1;
        int sy = y0p + dy, sx = x0p + dx;
        int pix0 = ((((unsigned)sy)  < 64u) & (((unsigned)sx) < 64u)) ? ((sy  << 6) + sx) : 4096;
        int sy1 = sy + 2;   // second slot is +128 pixels = +2 image rows
        int pix1 = ((((unsigned)sy1) < 64u) & (((unsigned)sx) < 64u)) ? ((sy1 << 6) + sx) : 4096;
        P0 = xb + (size_t)pix0 * 512 + qoff;
        P1 = xb + (size_t)pix1 * 512 + qoff;
    };

#define STAGE(SB, PA_OFF, Q0, Q1, B_OFF) { \
    GLL16(pA0 + (PA_OFF), &Ash[SB][t * 8]); \
    GLL16(pA1 + (PA_OFF), &Ash[SB][(t + 512) * 8]); \
    GLL16((Q0) + (B_OFF), &Bsh[SB][t * 8]); \
    GLL16((Q1) + (B_OFF), &Bsh[SB][(t + 512) * 8]); }

#define COMPUTE(CB) { \
    bf16x8 af[8], bf[4]; \
    _Pragma("unroll") for (int mi = 0; mi < 8; ++mi) \
        af[mi] = *(const bf16x8*)(&Ash[CB][arb + mi * 512]); \
    _Pragma("unroll") for (int ni = 0; ni < 4; ++ni) \
        bf[ni] = *(const bf16x8*)(&Bsh[CB][brb + ni * 512]); \
    __builtin_amdgcn_s_setprio(1); \
    _Pragma("unroll") for (int mi = 0; mi < 8; ++mi) \
        _Pragma("unroll") for (int ni = 0; ni < 4; ++ni) \
            acc[mi][ni] = __builtin_amdgcn_mfma_f32_16x16x32_bf16( \
                af[mi], bf[ni], acc[mi][ni], 0, 0, 0); \
    __builtin_amdgcn_s_setprio(0); }

    const __hip_bfloat16 *pB0, *pB1, *nB0, *nB1;
    bptrs(0, pB0, pB1);

    // prologue: stage chunks 0,1,2 into ring 0,1,2 (all tap 0)
    STAGE(0, 0,  pB0, pB1, 0);
    STAGE(1, 32, pB0, pB1, 32);
    STAGE(2, 64, pB0, pB1, 64);
    VMW(8);          // tile 0 resident (8 newest = tiles 1,2 may fly)
    BAR();

    for (int tap = 0; tap < 8; ++tap) {
        bptrs(tap + 1, nB0, nB1);
        #pragma unroll
        for (int ch = 0; ch < 16; ++ch) {
            // stage chunk kk+3 (kk = tap*16+ch); A offset linear: (ch+3)*32
            if (ch < 13) { STAGE((ch + 3) & 3, (ch + 3) * 32, pB0, pB1, (ch + 3) * 32); }
            else         { STAGE((ch + 3) & 3, (ch + 3) * 32, nB0, nB1, (ch - 13) * 32); }
            COMPUTE(ch & 3);
            VMW(8);      // tile kk+1 resident; tiles kk+2,kk+3 may fly
            BAR();
        }
        pA0 += 512; pA1 += 512;
        pB0 = nB0; pB1 = nB1;
    }
    // tap 8 (last): stage only while target chunk <= 143 (ch <= 12)
    #pragma unroll
    for (int ch = 0; ch < 16; ++ch) {
        if (ch <= 12) { STAGE((ch + 3) & 3, (ch + 3) * 32, pB0, pB1, (ch + 3) * 32); }
        COMPUTE(ch & 3);
        if      (ch < 13)  { VMW(8); BAR(); }
        else if (ch == 13) { VMW(4); BAR(); }
        else if (ch == 14) { VMW(0); BAR(); }
        // ch == 15: last compute, fall through to epilogue
    }
#undef STAGE
#undef COMPUTE

    #pragma unroll
    for (int mi = 0; mi < 8; ++mi) {
        int oc = oc0 + wm * 128 + mi * 16 + lq * 4;
        #pragma unroll
        for (int ni = 0; ni < 4; ++ni) {
            int n = n0 + wn * 64 + ni * 16 + lr;
            #pragma unroll
            for (int v = 0; v < 4; ++v) {
                float r = acc[mi][ni][v] + bias[oc + v];
                out[((size_t)(b * OC + oc + v)) * HW + n] = r;
            }
        }
    }
}

extern "C" void kernel_launch(void* const* d_in, const int* in_sizes, int n_in,
                              void* d_out, int out_size, void* d_ws, size_t ws_size,
                              hipStream_t stream) {
    const float* x      = (const float*)d_in[0];
    const float* style  = (const float*)d_in[1];
    const float* weight = (const float*)d_in[2];
    const float* bias   = (const float*)d_in[3];
    const float* mod_w  = (const float*)d_in[4];
    const float* mod_b  = (const float*)d_in[5];
    float* out = (float*)d_out;

    // ws: s [32KB] | wmod bf16 [75.5MB] | xT bf16 [67.2MB]
    float* s_ws = (float*)d_ws;
    __hip_bfloat16* wmod = (__hip_bfloat16*)((char*)d_ws + 32768);
    __hip_bfloat16* xT   = (__hip_bfloat16*)((char*)d_ws + 32768 + (size_t)16 * 512 * KTOT * 2);

    style_mod_kernel<<<2048, 256, 0, stream>>>(style, mod_w, mod_b, s_ws);
    wmod_kernel<<<16 * 512, 256, 0, stream>>>(weight, s_ws, wmod);
    zero_row_kernel<<<16, 256, 0, stream>>>(xT);
    dim3 tgrid(64, 8, 16);
    xpose_kernel<<<tgrid, 256, 0, stream>>>(x, xT);
    conv_kernel<<<512, 512, 0, stream>>>(xT, wmod, bias, out);
}

// Round 6
// 374.286 us; speedup vs baseline: 4.3460x; 1.0137x over previous
//
#include <hip/hip_runtime.h>
#include <hip/hip_bf16.h>

// ModulatedConv2d b=16, ic=oc=512, k=3, h=w=64.
// R6: R5 skeleton (256x256, BK=32, ring-4, counted vmcnt(8), involution
// swizzle = 0 conflicts) + 2-phase interleave per K-step (m201-style):
// each phase = {ds_read frag subtile | stage half | barrier | 16 MFMA},
// creating wave role-diversity so LDS pipe and MFMA pipe overlap (T3+T5).

typedef __bf16 bf16x8 __attribute__((ext_vector_type(8)));
typedef float  f32x4  __attribute__((ext_vector_type(4)));

#define IC   512
#define OC   512
#define HW   4096
#define KTOT 4608

typedef __attribute__((address_space(3))) unsigned lds_u32;
typedef const __attribute__((address_space(1))) unsigned glb_u32;
#define GLL16(gsrc, ldst) \
    __builtin_amdgcn_global_load_lds((glb_u32*)(gsrc), (lds_u32*)(ldst), 16, 0, 0)
#define VMW(N)  asm volatile("s_waitcnt vmcnt(" #N ")" ::: "memory")
#define BAR()   asm volatile("s_barrier" ::: "memory")
#define SCHED0() __builtin_amdgcn_sched_barrier(0)

// ---------------- kernel 1: style modulation s[b][i] ----------------
__global__ __launch_bounds__(256) void style_mod_kernel(
    const float* __restrict__ style, const float* __restrict__ mod_w,
    const float* __restrict__ mod_b, float* __restrict__ s_out)
{
    int pair = blockIdx.x * 4 + (threadIdx.x >> 6);
    int lane = threadIdx.x & 63;
    int b = pair >> 9;
    int i = pair & 511;
    const float4* sv = (const float4*)(style + b * 512);
    const float4* wv = (const float4*)(mod_w + i * 512);
    float4 a0 = sv[lane * 2], a1 = sv[lane * 2 + 1];
    float4 w0 = wv[lane * 2], w1 = wv[lane * 2 + 1];
    float sum = a0.x*w0.x + a0.y*w0.y + a0.z*w0.z + a0.w*w0.w
              + a1.x*w1.x + a1.y*w1.y + a1.z*w1.z + a1.w*w1.w;
    #pragma unroll
    for (int off = 32; off; off >>= 1) sum += __shfl_xor(sum, off);
    if (lane == 0) s_out[pair] = sum + mod_b[i];
}

// ------------- kernel 2: demod + bf16 wmod, layout [b][oc][tap*512+ic] -------------
__global__ __launch_bounds__(256) void wmod_kernel(
    const float* __restrict__ weight,   // [512][4608] (e = ic*9+tap)
    const float* __restrict__ s_in,
    __hip_bfloat16* __restrict__ wmod)  // [16*512][4608] (e' = tap*512+ic)
{
    int b  = blockIdx.x >> 9;
    int oc = blockIdx.x & 511;
    __shared__ float s_sh[512];
    __shared__ float red[256];
    int t = threadIdx.x;
    s_sh[t]       = s_in[b * 512 + t];
    s_sh[t + 256] = s_in[b * 512 + t + 256];
    __syncthreads();
    const float* wrow = weight + (size_t)oc * KTOT;
    float partial = 0.f;
    for (int e = t; e < KTOT; e += 256) {
        float v = wrow[e] * s_sh[e / 9];
        partial += v * v;
    }
    red[t] = partial;
    __syncthreads();
    #pragma unroll
    for (int off = 128; off; off >>= 1) {
        if (t < off) red[t] += red[t + off];
        __syncthreads();
    }
    float demod = rsqrtf(red[0] + 1e-8f);
    __hip_bfloat16* dst = wmod + (size_t)blockIdx.x * KTOT;
    for (int ep = t; ep < KTOT; ep += 256) {
        int tap = ep >> 9, ic = ep & 511;
        dst[ep] = __float2bfloat16(wrow[ic * 9 + tap] * s_sh[ic] * demod);
    }
}

// ------------- kernel 3a: zero pad row of xT -------------
__global__ void zero_row_kernel(__hip_bfloat16* xT) {
    ((unsigned*)(xT + ((size_t)blockIdx.x * 4097 + 4096) * 512))[threadIdx.x] = 0u;
}

// ------------- kernel 3b: x [b][ic][pix] f32 -> xT [b][pix][ic] bf16 -------------
__global__ __launch_bounds__(256) void xpose_kernel(
    const float* __restrict__ x, __hip_bfloat16* __restrict__ xT)
{
    __shared__ __align__(16) float tile[64][68];
    int b = blockIdx.z, ic0 = blockIdx.y * 64, p0 = blockIdx.x * 64;
    int t = threadIdx.x;
    const float* xb = x + ((size_t)b * 512 + ic0) * 4096 + p0;
    int rr = t >> 4, cc = (t & 15) * 4;
    #pragma unroll
    for (int i = 0; i < 4; ++i) {
        float4 v = *(const float4*)(xb + (size_t)(rr + i * 16) * 4096 + cc);
        *(float4*)&tile[rr + i * 16][cc] = v;
    }
    __syncthreads();
    int pr = t >> 2, io = (t & 3) * 16;
    __hip_bfloat16 obuf[16];
    #pragma unroll
    for (int j = 0; j < 16; ++j) obuf[j] = __float2bfloat16(tile[io + j][pr]);
    __hip_bfloat16* dst = xT + ((size_t)b * 4097 + p0 + pr) * 512 + ic0 + io;
    *(uint4*)dst       = *(uint4*)&obuf[0];
    *(uint4*)(dst + 8) = *(uint4*)&obuf[8];
}

// ------------- kernel 4: conv, 256x256 ring-4, 2-phase interleave -------------
__global__ __launch_bounds__(512, 2) void conv_kernel(
    const __hip_bfloat16* __restrict__ xT,    // [16][4097][512]
    const __hip_bfloat16* __restrict__ wmod,  // [16*512][4608]
    const float* __restrict__ bias,
    float* __restrict__ out)                  // [16][512][4096]
{
    __shared__ __align__(16) __hip_bfloat16 Ash[4][256 * 32];
    __shared__ __align__(16) __hip_bfloat16 Bsh[4][256 * 32];

    const int t    = threadIdx.x;
    const int lane = t & 63;
    const int wid  = t >> 6;      // 0..7
    const int wm   = wid >> 2;    // 0..1 (M half)
    const int wn   = wid & 3;     // 0..3 (N quarter)
    const int lr   = lane & 15;
    const int lq   = lane >> 4;

    // block decode: 512 blocks; per XCD 2 b's; oc-tile inner (B-panel L2 reuse)
    int bid = blockIdx.x;
    int xcd = bid & 7, idx = bid >> 3;
    int oc1 = idx & 1;
    int nt  = (idx >> 1) & 15;
    int bb  = (idx >> 5) & 1;
    int b   = xcd * 2 + bb;
    int oc0 = oc1 * 256, n0 = nt * 256;

    const __hip_bfloat16* wb = wmod + (size_t)(b * 512 + oc0) * KTOT;
    const __hip_bfloat16* xb = xT + (size_t)b * 4097 * 512;

    // stage geometry: slot u (t, t+512): row u>>2, phys quad u&3.
    // involution swizzle (verified 0 conflicts): logical quad = (u&3)^((u>>3)&3).
    const int qoff = (((t & 3) ^ ((t >> 3) & 3)) * 8);
    const int srow = t >> 2;                 // 0..127 (second slot: +128)
    const int p0g  = n0 + srow;
    const int y0p  = p0g >> 6, x0p = p0g & 63;

    const __hip_bfloat16* pA0 = wb + (size_t)srow * KTOT + qoff;
    const __hip_bfloat16* pA1 = pA0 + (size_t)128 * KTOT;

    // fragment-read bases with matching swizzle
    const int swq = (lq ^ ((lr >> 1) & 3)) * 8;
    const int arb = (wm * 128 + lr) * 32 + swq;
    const int brb = (wn * 64  + lr) * 32 + swq;

    f32x4 acc[8][4] = {};

    // per-tap B row pointers (pixel shifted by (dy,dx); OOB -> zero row 4096)
    auto bptrs = [&](int tap, const __hip_bfloat16*& P0, const __hip_bfloat16*& P1) {
        int dy = tap / 3 - 1, dx = tap % 3 - 1;
        int sy = y0p + dy, sx = x0p + dx;
        int pix0 = ((((unsigned)sy)  < 64u) & (((unsigned)sx) < 64u)) ? ((sy  << 6) + sx) : 4096;
        int sy1 = sy + 2;   // second slot is +128 pixels = +2 image rows
        int pix1 = ((((unsigned)sy1) < 64u) & (((unsigned)sx) < 64u)) ? ((sy1 << 6) + sx) : 4096;
        P0 = xb + (size_t)pix0 * 512 + qoff;
        P1 = xb + (size_t)pix1 * 512 + qoff;
    };

#define STAGE_A(SB, OFF) { \
    GLL16(pA0 + (OFF), &Ash[SB][t * 8]); \
    GLL16(pA1 + (OFF), &Ash[SB][(t + 512) * 8]); }
#define STAGE_B(SB, Q0, Q1, OFF) { \
    GLL16((Q0) + (OFF), &Bsh[SB][t * 8]); \
    GLL16((Q1) + (OFF), &Bsh[SB][(t + 512) * 8]); }

#define MFMA_HALF(MB) { \
    __builtin_amdgcn_s_setprio(1); \
    _Pragma("unroll") for (int mi = 0; mi < 4; ++mi) \
        _Pragma("unroll") for (int ni = 0; ni < 4; ++ni) \
            acc[(MB) + mi][ni] = __builtin_amdgcn_mfma_f32_16x16x32_bf16( \
                af[mi], bfr[ni], acc[(MB) + mi][ni], 0, 0, 0); \
    __builtin_amdgcn_s_setprio(0); }

    const __hip_bfloat16 *pB0, *pB1, *nB0, *nB1;
    bptrs(0, pB0, pB1);

    // prologue: stage chunks 0,1,2 into ring 0,1,2 (all tap 0)
    STAGE_A(0, 0);  STAGE_B(0, pB0, pB1, 0);
    STAGE_A(1, 32); STAGE_B(1, pB0, pB1, 32);
    STAGE_A(2, 64); STAGE_B(2, pB0, pB1, 64);
    VMW(8);          // tile 0 resident (tiles 1,2 may fly)
    BAR();

    for (int tap = 0; tap < 8; ++tap) {
        bptrs(tap + 1, nB0, nB1);
        #pragma unroll
        for (int ch = 0; ch < 16; ++ch) {
            const int cb = ch & 3, sb = (ch + 3) & 3;
            bf16x8 af[4], bfr[4];
            // ---- phase 0: read A-low + all B frags; stage next A ----
            #pragma unroll
            for (int mi = 0; mi < 4; ++mi)
                af[mi] = *(const bf16x8*)(&Ash[cb][arb + mi * 512]);
            #pragma unroll
            for (int ni = 0; ni < 4; ++ni)
                bfr[ni] = *(const bf16x8*)(&Bsh[cb][brb + ni * 512]);
            STAGE_A(sb, (ch + 3) * 32);   // (16+c)*32 = 512+c*32 spans into next tap: exact
            BAR(); SCHED0();
            MFMA_HALF(0);
            BAR();
            // ---- phase 1: read A-high; stage next B ----
            #pragma unroll
            for (int mi = 0; mi < 4; ++mi)
                af[mi] = *(const bf16x8*)(&Ash[cb][arb + (4 + mi) * 512]);
            if (ch < 13) { STAGE_B(sb, pB0, pB1, (ch + 3) * 32); }
            else         { STAGE_B(sb, nB0, nB1, (ch - 13) * 32); }
            BAR(); SCHED0();
            MFMA_HALF(4);
            VMW(8);      // tile kk+1 resident; kk+2,kk+3 may fly
            BAR();
        }
        pA0 += 512; pA1 += 512;
        pB0 = nB0; pB1 = nB1;
    }
    // tap 8 (last): stage only while target chunk <= 143 (ch <= 12)
    #pragma unroll
    for (int ch = 0; ch < 16; ++ch) {
        const int cb = ch & 3, sb = (ch + 3) & 3;
        bf16x8 af[4], bfr[4];
        #pragma unroll
        for (int mi = 0; mi < 4; ++mi)
            af[mi] = *(const bf16x8*)(&Ash[cb][arb + mi * 512]);
        #pragma unroll
        for (int ni = 0; ni < 4; ++ni)
            bfr[ni] = *(const bf16x8*)(&Bsh[cb][brb + ni * 512]);
        if (ch <= 12) STAGE_A(sb, (ch + 3) * 32);
        BAR(); SCHED0();
        MFMA_HALF(0);
        BAR();
        #pragma unroll
        for (int mi = 0; mi < 4; ++mi)
            af[mi] = *(const bf16x8*)(&Ash[cb][arb + (4 + mi) * 512]);
        if (ch <= 12) STAGE_B(sb, pB0, pB1, (ch + 3) * 32);
        BAR(); SCHED0();
        MFMA_HALF(4);
        if      (ch < 13)  { VMW(8); BAR(); }
        else if (ch == 13) { VMW(4); BAR(); }
        else if (ch == 14) { VMW(0); BAR(); }
        // ch == 15: last compute, fall through to epilogue
    }
#undef STAGE_A
#undef STAGE_B
#undef MFMA_HALF

    #pragma unroll
    for (int mi = 0; mi < 8; ++mi) {
        int oc = oc0 + wm * 128 + mi * 16 + lq * 4;
        #pragma unroll
        for (int ni = 0; ni < 4; ++ni) {
            int n = n0 + wn * 64 + ni * 16 + lr;
            #pragma unroll
            for (int v = 0; v < 4; ++v) {
                float r = acc[mi][ni][v] + bias[oc + v];
                out[((size_t)(b * OC + oc + v)) * HW + n] = r;
            }
        }
    }
}

extern "C" void kernel_launch(void* const* d_in, const int* in_sizes, int n_in,
                              void* d_out, int out_size, void* d_ws, size_t ws_size,
                              hipStream_t stream) {
    const float* x      = (const float*)d_in[0];
    const float* style  = (const float*)d_in[1];
    const float* weight = (const float*)d_in[2];
    const float* bias   = (const float*)d_in[3];
    const float* mod_w  = (const float*)d_in[4];
    const float* mod_b  = (const float*)d_in[5];
    float* out = (float*)d_out;

    // ws: s [32KB] | wmod bf16 [75.5MB] | xT bf16 [67.2MB]
    float* s_ws = (float*)d_ws;
    __hip_bfloat16* wmod = (__hip_bfloat16*)((char*)d_ws + 32768);
    __hip_bfloat16* xT   = (__hip_bfloat16*)((char*)d_ws + 32768 + (size_t)16 * 512 * KTOT * 2);

    style_mod_kernel<<<2048, 256, 0, stream>>>(style, mod_w, mod_b, s_ws);
    wmod_kernel<<<16 * 512, 256, 0, stream>>>(weight, s_ws, wmod);
    zero_row_kernel<<<16, 256, 0, stream>>>(xT);
    dim3 tgrid(64, 8, 16);
    xpose_kernel<<<tgrid, 256, 0, stream>>>(x, xT);
    conv_kernel<<<512, 512, 0, stream>>>(xT, wmod, bias, out);
}